// Round 9
// baseline (212.746 us; speedup 1.0000x reference)
//
#include <hip/hip_runtime.h>
#include <cstdint>

// ---------------------------------------------------------------------------
// CTC loss pipeline (3 launches):
//   k_prep : x fp32->bf16, W[D,V] -> Wt[V,D] bf16, zero d_out
//   k_fused: GEMM + bias + log_softmax + ext-label gather -> pext, fused.
//            Block = 64 rows x V cols, 16 waves, 1 block/CU. A-tile staged to
//            dynamic LDS once; B direct from L2-resident Wt; no K-loop
//            barriers; logits never written to global.
//   k_ctc  : 4-deep pipelined scaled linear-domain CTC forward, atomic mean.
// ---------------------------------------------------------------------------

#define SPAD 260                      // padded extended-state row (257 -> 260)
#define PEXT_PAD_ROWS 64              // prefetch overrun pad (loaded, never consumed)
#define L2E 1.4426950408889634f
#define LN2 0.6931471805599453f

typedef short v8s __attribute__((ext_vector_type(8)));
typedef float v4f __attribute__((ext_vector_type(4)));

__device__ __forceinline__ uint32_t f2bf_bits(float f) {
  uint32_t u = __float_as_uint(f);
  return (u + 0x7FFFu + ((u >> 16) & 1u)) >> 16;   // RNE
}
__device__ __forceinline__ float bf2f(uint32_t h) { return __uint_as_float(h << 16); }

// ---------------- k_prep: x fp32->bf16, W transpose->bf16, zero d_out ----------------
__global__ void k_prep(const float* __restrict__ x, uint16_t* __restrict__ xb, long long n,
                       const float* __restrict__ W, uint16_t* __restrict__ Wt, int D, int V,
                       float* __restrict__ out, int nconv) {
  if (blockIdx.x == 0 && threadIdx.x == 0) out[0] = 0.f;   // zero the atomic target
  if ((int)blockIdx.x < nconv) {
    long long i = ((long long)blockIdx.x * blockDim.x + threadIdx.x) * 8;
    if (i >= n) return;
    float4 a = *(const float4*)(x + i);
    float4 b = *(const float4*)(x + i + 4);
    uint4 o;
    o.x = f2bf_bits(a.x) | (f2bf_bits(a.y) << 16);
    o.y = f2bf_bits(a.z) | (f2bf_bits(a.w) << 16);
    o.z = f2bf_bits(b.x) | (f2bf_bits(b.y) << 16);
    o.w = f2bf_bits(b.z) | (f2bf_bits(b.w) << 16);
    *(uint4*)(xb + i) = o;
  } else {
    __shared__ float tile[32][33];
    const int bid2 = blockIdx.x - nconv;
    const int n0 = (bid2 % (V / 32)) * 32, k0 = (bid2 / (V / 32)) * 32;
    const int tx = threadIdx.x & 31, ty = threadIdx.x >> 5;   // (32,8)
    #pragma unroll
    for (int i = 0; i < 32; i += 8)
      tile[ty + i][tx] = W[(size_t)(k0 + ty + i) * V + n0 + tx];
    __syncthreads();
    #pragma unroll
    for (int i = 0; i < 32; i += 8)
      Wt[(size_t)(n0 + ty + i) * D + k0 + tx] = (uint16_t)f2bf_bits(tile[tx][ty + i]);
  }
}

// ---------------- k_fused: GEMM + softmax + gather -> pext ----------------
// A:[M,K] bf16 (xb), Bt:[V,K] bf16 (=W^T). Block: rows m0..m0+63, ALL V cols.
// 16 waves; wave w owns cols [64w, 64w+64) and all 64 rows.
// Dynamic LDS: As 64x(K+8) bf16 | red_mx[64][16] | red_sm[64][16] | lse2s[64] | pblank[64].
// Requires V == 64*16, T%64==0, K%32==0, K<=512.
__global__ __launch_bounds__(1024, 1) void k_fused(const uint16_t* __restrict__ A,
                                                   const uint16_t* __restrict__ Bt,
                                                   const float* __restrict__ bias,
                                                   const int* __restrict__ target,
                                                   const int* __restrict__ tlen,
                                                   float* __restrict__ pext,
                                                   int T, int K, int L) {
  extern __shared__ char smem[];
  const int astr = K + 8;                       // bf16 row stride (+8 -> 2-way banks, free)
  uint16_t* As = (uint16_t*)smem;
  float* red_mx = (float*)(smem + (size_t)64 * astr * 2);
  float* red_sm = red_mx + 64 * 16;
  float* lse2s  = red_sm + 64 * 16;
  float* pblank = lse2s + 64;

  const int tid = threadIdx.x, lane = tid & 63, wave = tid >> 6;
  const int ccol = lane & 15, q = lane >> 4;    // MFMA lane mapping (frow=ccol for frags)
  const int m0 = blockIdx.x * 64;

  // ---- stage A-tile: wave stages rows wave*4..+3, one row per instruction ----
  #pragma unroll
  for (int i = 0; i < 4; i++) {
    const int r = wave * 4 + i;                 // wave-uniform
    for (int kc = 0; kc < K; kc += 512) {
      const uint16_t* ga = A + (size_t)(m0 + r) * K + kc + lane * 8;
      __builtin_amdgcn_global_load_lds(
          (const __attribute__((address_space(1))) void*)ga,
          (__attribute__((address_space(3))) void*)(As + r * astr + kc + lane * 8), 16, 0, 0);
    }
  }
  __syncthreads();   // only barrier before the epilogue

  // ---- K-loop: B direct from L2, A from LDS, no barriers ----
  const uint16_t* Bw = Bt + (size_t)(wave * 64) * K;
  v4f acc[4][4] = {};
  for (int k0 = 0; k0 < K; k0 += 32) {
    v8s bfr[4], af[4];
    #pragma unroll
    for (int j = 0; j < 4; j++)
      bfr[j] = *(const v8s*)(Bw + (size_t)(j * 16 + ccol) * K + k0 + q * 8);
    #pragma unroll
    for (int i = 0; i < 4; i++)
      af[i] = *(const v8s*)(As + (i * 16 + ccol) * astr + k0 + q * 8);
    #pragma unroll
    for (int i = 0; i < 4; i++)
      #pragma unroll
      for (int j = 0; j < 4; j++)
        acc[i][j] = __builtin_amdgcn_mfma_f32_16x16x32_bf16(af[i], bfr[j], acc[i][j], 0, 0, 0);
  }

  // ---- bias ----  C/D layout: col = ccol, row = i*16 + 4q + r2  [m89-verified]
  float bv[4];
  #pragma unroll
  for (int j = 0; j < 4; j++) bv[j] = bias[wave * 64 + j * 16 + ccol];
  #pragma unroll
  for (int i = 0; i < 4; i++)
    #pragma unroll
    for (int j = 0; j < 4; j++)
      #pragma unroll
      for (int r2 = 0; r2 < 4; r2++) acc[i][j][r2] += bv[j];

  // ---- per-wave row stats over its 64 cols ----
  #pragma unroll
  for (int i = 0; i < 4; i++)
    #pragma unroll
    for (int r2 = 0; r2 < 4; r2++) {
      float m = fmaxf(fmaxf(acc[i][0][r2], acc[i][1][r2]), fmaxf(acc[i][2][r2], acc[i][3][r2]));
      #pragma unroll
      for (int off = 1; off < 16; off <<= 1) m = fmaxf(m, __shfl_xor(m, off, 64));
      float s = 0.f;
      #pragma unroll
      for (int j = 0; j < 4; j++) s += exp2f((acc[i][j][r2] - m) * L2E);
      #pragma unroll
      for (int off = 1; off < 16; off <<= 1) s += __shfl_xor(s, off, 64);
      if (ccol == 0) {
        const int row = i * 16 + 4 * q + r2;
        red_mx[row * 16 + wave] = m;
        red_sm[row * 16 + wave] = s;
      }
    }
  __syncthreads();

  // ---- cross-wave lse per row ----
  if (tid < 64) {
    float M = -INFINITY;
    #pragma unroll
    for (int w = 0; w < 16; w++) M = fmaxf(M, red_mx[tid * 16 + w]);
    float S = 0.f;
    #pragma unroll
    for (int w = 0; w < 16; w++) S += red_sm[tid * 16 + w] * exp2f((red_mx[tid * 16 + w] - M) * L2E);
    lse2s[tid] = M * L2E + log2f(S);
  }
  __syncthreads();

  // ---- blank-column probs (col 0 lives in wave 0) ----
  if (wave == 0 && ccol == 0) {
    #pragma unroll
    for (int i = 0; i < 4; i++)
      #pragma unroll
      for (int r2 = 0; r2 < 4; r2++) {
        const int row = i * 16 + 4 * q + r2;
        pblank[row] = exp2f(acc[i][0][r2] * L2E - lse2s[row]);
      }
  }

  // ---- odd-s entries: each label belongs to exactly one wave ----
  const int b = m0 / T;
  const int Lb = tlen[b];
  const int S = 2 * Lb + 1;
  const int* tg = target + b * L;
  for (int li = 0; li < Lb; li++) {
    const int lbl = tg[li];
    if ((lbl >> 6) != wave) continue;           // wave-uniform skip
    if (ccol == (lbl & 15)) {
      const int j = (lbl >> 4) & 3;
      #pragma unroll
      for (int i = 0; i < 4; i++)
        #pragma unroll
        for (int r2 = 0; r2 < 4; r2++) {
          const int row = i * 16 + 4 * q + r2;
          pext[(size_t)(m0 + row) * SPAD + 2 * li + 1] =
              exp2f(acc[i][j][r2] * L2E - lse2s[row]);
        }
    }
  }
  __syncthreads();   // pblank ready

  // ---- even-s + tail: wave handles rows wave*4..+3 ----
  #pragma unroll
  for (int rr = 0; rr < 4; rr++) {
    const int row = wave * 4 + rr;
    const float pb = pblank[row];
    float* prow = pext + (size_t)(m0 + row) * SPAD;
    for (int s = lane; s < SPAD; s += 64) {
      if (s >= S)       prow[s] = 0.f;
      else if (!(s & 1)) prow[s] = pb;
    }
  }
}

// ---------------- k_ctc: scaled linear-domain CTC forward, 1 wave per batch ----------------
__device__ __forceinline__ float wave_shr1(float x) {   // lane l <- lane l-1, lane0 <- 0
  return __int_as_float(__builtin_amdgcn_update_dpp(0, __float_as_int(x), 0x138, 0xf, 0xf, true));
}
__device__ __forceinline__ float wave_max_nonneg(float x) {
  x = fmaxf(x, __int_as_float(__builtin_amdgcn_update_dpp(0, __float_as_int(x), 0x111, 0xf, 0xf, true)));
  x = fmaxf(x, __int_as_float(__builtin_amdgcn_update_dpp(0, __float_as_int(x), 0x112, 0xf, 0xf, true)));
  x = fmaxf(x, __int_as_float(__builtin_amdgcn_update_dpp(0, __float_as_int(x), 0x114, 0xf, 0xf, true)));
  x = fmaxf(x, __int_as_float(__builtin_amdgcn_update_dpp(0, __float_as_int(x), 0x118, 0xf, 0xf, true)));
  x = fmaxf(x, __int_as_float(__builtin_amdgcn_update_dpp(0, __float_as_int(x), 0x142, 0xf, 0xf, true)));
  x = fmaxf(x, __int_as_float(__builtin_amdgcn_update_dpp(0, __float_as_int(x), 0x143, 0xf, 0xf, true)));
  return __int_as_float(__builtin_amdgcn_readlane(__float_as_int(x), 63));
}

__device__ __forceinline__ void load8(float4* __restrict__ p, float* __restrict__ p4,
                                      const float* __restrict__ pb, int t0, int lane) {
  #pragma unroll
  for (int k = 0; k < 8; k++) {
    const float* row = pb + (size_t)(t0 + k) * SPAD;
    p[k] = *(const float4*)(row + (lane << 2));
    p4[k] = row[256];               // wave-broadcast load
  }
}

__global__ __launch_bounds__(64, 1) void k_ctc(const float* __restrict__ pext,
                                               const int* __restrict__ target,
                                               const int* __restrict__ ilen,
                                               const int* __restrict__ tlen,
                                               float* __restrict__ out, int T, int L) {
  const int b = blockIdx.x;
  const int lane = threadIdx.x;          // 64 threads = 1 wave
  const int B = gridDim.x;
  const int Tb = ilen[b];
  const int Lb = tlen[b];
  const int S = 2 * Lb + 1;
  const int* tg = target + b * L;

  const int s1 = 4 * lane + 1, s3 = 4 * lane + 3;
  float sk1 = 0.f, sk3 = 0.f;
  if (s1 >= 3 && s1 < S) sk1 = (tg[(s1 - 1) >> 1] != tg[(s1 - 3) >> 1]) ? 1.f : 0.f;
  if (s3 >= 3 && s3 < S) sk3 = (tg[(s3 - 1) >> 1] != tg[(s3 - 3) >> 1]) ? 1.f : 0.f;

  const float* pb = pext + (size_t)b * T * SPAD;
  const float4 p0 = *(const float4*)(pb + (lane << 2));
  float a0 = (lane == 0) ? p0.x : 0.f;
  float a1 = (lane == 0) ? p0.y : 0.f;
  float a2 = 0.f, a3 = 0.f, a4 = 0.f;
  float log2C = 0.f;

  #define CTC_STEP(PP, P4) {                                            \
    const float pm3 = wave_shr1(a3);                                    \
    const float a255 = __int_as_float(__builtin_amdgcn_readlane(__float_as_int(a3), 63)); \
    const float n0v = (a0 + pm3) * (PP).x;                              \
    const float n1v = (a1 + a0 + sk1 * pm3) * (PP).y;                   \
    const float n2v = (a2 + a1) * (PP).z;                               \
    const float n3v = (a3 + a2 + sk3 * a1) * (PP).w;                    \
    const float n4v = (a4 + a255) * (P4);                               \
    a0 = n0v; a1 = n1v; a2 = n2v; a3 = n3v; a4 = n4v; }

  #define RENORM {                                                      \
    float m = fmaxf(fmaxf(fmaxf(a0, a1), fmaxf(a2, a3)), a4);           \
    m = wave_max_nonneg(m);                                             \
    const int e = (int)((__float_as_uint(m) >> 23) & 255u) - 127;       \
    const float scale = __uint_as_float((uint32_t)(127 - e) << 23);     \
    a0 *= scale; a1 *= scale; a2 *= scale; a3 *= scale; a4 *= scale;    \
    log2C += (float)e; }

  float4 Pa[8], Pb_[8], Pc[8], Pd[8];
  float Qa[8], Qb[8], Qc[8], Qd[8];
  int t0 = 1;
  bool done = false;
  load8(Pa, Qa, pb, t0, lane);
  load8(Pb_, Qb, pb, t0 + 8, lane);
  load8(Pc, Qc, pb, t0 + 16, lane);
  __builtin_amdgcn_sched_barrier(0);

  #define PHASE(LP, LQ, CP, CQ) {                                       \
    if (t0 + 8 <= Tb) {                                                 \
      load8(LP, LQ, pb, t0 + 24, lane);                                 \
      __builtin_amdgcn_sched_barrier(0);                                \
      _Pragma("unroll")                                                 \
      for (int k = 0; k < 8; k++) CTC_STEP(CP[k], CQ[k]);               \
      RENORM; t0 += 8;                                                  \
    } else {                                                            \
      _Pragma("unroll")                                                 \
      for (int k = 0; k < 8; k++) { if (t0 + k < Tb) CTC_STEP(CP[k], CQ[k]); } \
      RENORM; done = true;                                              \
    } }

  while (!done) {
    PHASE(Pd, Qd, Pa, Qa); if (done) break;
    PHASE(Pa, Qa, Pb_, Qb); if (done) break;
    PHASE(Pb_, Qb, Pc, Qc); if (done) break;
    PHASE(Pc, Qc, Pd, Qd);
  }

  __shared__ float abuf[257];
  abuf[4 * lane + 0] = a0; abuf[4 * lane + 1] = a1;
  abuf[4 * lane + 2] = a2; abuf[4 * lane + 3] = a3;
  if (lane == 63) abuf[256] = a4;
  __syncthreads();
  if (lane == 0) {
    const float ssum = abuf[2 * Lb - 1] + abuf[2 * Lb];
    const float ll = (log2f(ssum) + log2C) * LN2;
    float nll = -ll;
    if (!(nll < 1e29f)) nll = 0.f;                 // zero_infinity (also catches inf/nan)
    atomicAdd(out, nll / ((float)(Lb > 0 ? Lb : 1) * (float)B));
  }
}

// ---------------------------------------------------------------------------
extern "C" void kernel_launch(void* const* d_in, const int* in_sizes, int n_in,
                              void* d_out, int out_size, void* d_ws, size_t ws_size,
                              hipStream_t stream) {
  const float* x      = (const float*)d_in[0];
  const float* W      = (const float*)d_in[1];
  const float* bias   = (const float*)d_in[2];
  const int*  target  = (const int*)d_in[3];
  const int*  ilen    = (const int*)d_in[4];
  const int*  tlen    = (const int*)d_in[5];

  const int B = in_sizes[4];
  const int V = in_sizes[2];
  const int D = in_sizes[1] / V;
  const int T = in_sizes[0] / (B * D);
  const int L = in_sizes[3] / B;
  const int M = B * T;

  char* ws = (char*)d_ws;
  const size_t xb_bytes = (size_t)M * D * 2;
  const size_t wt_bytes = (size_t)V * D * 2;
  uint16_t* xb = (uint16_t*)ws;
  uint16_t* Wt = (uint16_t*)(ws + xb_bytes);
  float* pext = (float*)(ws + xb_bytes + wt_bytes);

  const long long nx = (long long)M * D;
  const int nconv = (int)((nx / 8 + 255) / 256);
  const int ntrans = (V / 32) * (D / 32);
  k_prep<<<nconv + ntrans, 256, 0, stream>>>(x, xb, nx, W, Wt, D, V, (float*)d_out, nconv);

  const int smem = 64 * (D + 8) * 2 + 64 * 16 * 4 * 2 + 64 * 4 * 2;   // As | red | lse+pblank
  hipFuncSetAttribute((const void*)k_fused, hipFuncAttributeMaxDynamicSharedMemorySize, smem);
  k_fused<<<M / 64, 1024, smem, stream>>>(xb, Wt, bias, target, tlen, pext, T, D, L);

  k_ctc<<<B, 64, 0, stream>>>(pext, target, ilen, tlen, (float*)d_out, T, L);
}

// Round 10
// 187.014 us; speedup vs baseline: 1.1376x; 1.1376x over previous
//
#include <hip/hip_runtime.h>
#include <cstdint>

// ---------------------------------------------------------------------------
// CTC loss pipeline (3 launches):
//   k_prep : x fp32->bf16, W[D,V] -> Wt[V,D] bf16, zero d_out
//   k_fused: GEMM + bias + log_softmax + ext-label gather -> pext, fused.
//            Block = 64 rows x V cols, 16 waves, 1 block/CU. A-tile staged to
//            dynamic LDS once; B direct from L2-resident Wt; no K-loop
//            barriers; logits never written to global. ALL acc indexing is
//            compile-time (runtime-j indexing spilled acc to scratch in R9:
//            VGPR=52, 200 MB scratch WRITE).
//   k_ctc  : 4-deep pipelined scaled linear-domain CTC forward, atomic mean.
// ---------------------------------------------------------------------------

#define SPAD 260                      // padded extended-state row (257 -> 260)
#define PEXT_PAD_ROWS 64              // prefetch overrun pad (loaded, never consumed)
#define L2E 1.4426950408889634f
#define LN2 0.6931471805599453f

typedef short v8s __attribute__((ext_vector_type(8)));
typedef float v4f __attribute__((ext_vector_type(4)));

__device__ __forceinline__ uint32_t f2bf_bits(float f) {
  uint32_t u = __float_as_uint(f);
  return (u + 0x7FFFu + ((u >> 16) & 1u)) >> 16;   // RNE
}
__device__ __forceinline__ float bf2f(uint32_t h) { return __uint_as_float(h << 16); }

// ---------------- k_prep: x fp32->bf16, W transpose->bf16, zero d_out ----------------
__global__ void k_prep(const float* __restrict__ x, uint16_t* __restrict__ xb, long long n,
                       const float* __restrict__ W, uint16_t* __restrict__ Wt, int D, int V,
                       float* __restrict__ out, int nconv) {
  if (blockIdx.x == 0 && threadIdx.x == 0) out[0] = 0.f;   // zero the atomic target
  if ((int)blockIdx.x < nconv) {
    long long i = ((long long)blockIdx.x * blockDim.x + threadIdx.x) * 8;
    if (i >= n) return;
    float4 a = *(const float4*)(x + i);
    float4 b = *(const float4*)(x + i + 4);
    uint4 o;
    o.x = f2bf_bits(a.x) | (f2bf_bits(a.y) << 16);
    o.y = f2bf_bits(a.z) | (f2bf_bits(a.w) << 16);
    o.z = f2bf_bits(b.x) | (f2bf_bits(b.y) << 16);
    o.w = f2bf_bits(b.z) | (f2bf_bits(b.w) << 16);
    *(uint4*)(xb + i) = o;
  } else {
    __shared__ float tile[32][33];
    const int bid2 = blockIdx.x - nconv;
    const int n0 = (bid2 % (V / 32)) * 32, k0 = (bid2 / (V / 32)) * 32;
    const int tx = threadIdx.x & 31, ty = threadIdx.x >> 5;   // (32,8)
    #pragma unroll
    for (int i = 0; i < 32; i += 8)
      tile[ty + i][tx] = W[(size_t)(k0 + ty + i) * V + n0 + tx];
    __syncthreads();
    #pragma unroll
    for (int i = 0; i < 32; i += 8)
      Wt[(size_t)(n0 + ty + i) * D + k0 + tx] = (uint16_t)f2bf_bits(tile[tx][ty + i]);
  }
}

// ---------------- k_fused: GEMM + softmax + gather -> pext ----------------
// A:[M,K] bf16 (xb), Bt:[V,K] bf16 (=W^T). Block: rows m0..m0+63, ALL V cols.
// 16 waves; wave w owns cols [64w, 64w+64) and all 64 rows.
// Dynamic LDS: As 64x(K+8) bf16 | red_mx[64][16] | red_sm[64][16] | lse2s[64] | pblank[64].
// Requires V == 64*16, T%64==0, K%32==0, K<=512.
__global__ __launch_bounds__(1024, 1) void k_fused(const uint16_t* __restrict__ A,
                                                   const uint16_t* __restrict__ Bt,
                                                   const float* __restrict__ bias,
                                                   const int* __restrict__ target,
                                                   const int* __restrict__ tlen,
                                                   float* __restrict__ pext,
                                                   int T, int K, int L) {
  extern __shared__ char smem[];
  const int astr = K + 8;                       // bf16 row stride (+8 -> 2-way banks, free)
  uint16_t* As = (uint16_t*)smem;
  float* red_mx = (float*)(smem + (size_t)64 * astr * 2);
  float* red_sm = red_mx + 64 * 16;
  float* lse2s  = red_sm + 64 * 16;
  float* pblank = lse2s + 64;

  const int tid = threadIdx.x, lane = tid & 63, wave = tid >> 6;
  const int ccol = lane & 15, q = lane >> 4;    // MFMA lane mapping (frow=ccol for frags)
  const int m0 = blockIdx.x * 64;

  // ---- stage A-tile: wave stages rows wave*4..+3, one row per instruction ----
  #pragma unroll
  for (int i = 0; i < 4; i++) {
    const int r = wave * 4 + i;                 // wave-uniform
    for (int kc = 0; kc < K; kc += 512) {
      const uint16_t* ga = A + (size_t)(m0 + r) * K + kc + lane * 8;
      __builtin_amdgcn_global_load_lds(
          (const __attribute__((address_space(1))) void*)ga,
          (__attribute__((address_space(3))) void*)(As + r * astr + kc + lane * 8), 16, 0, 0);
    }
  }
  __syncthreads();   // only barrier before the epilogue

  // ---- K-loop: B direct from L2, A from LDS, no barriers ----
  const uint16_t* Bw = Bt + (size_t)(wave * 64) * K;
  v4f acc[4][4] = {};
  for (int k0 = 0; k0 < K; k0 += 32) {
    v8s bfr[4], af[4];
    #pragma unroll
    for (int j = 0; j < 4; j++)
      bfr[j] = *(const v8s*)(Bw + (size_t)(j * 16 + ccol) * K + k0 + q * 8);
    #pragma unroll
    for (int i = 0; i < 4; i++)
      af[i] = *(const v8s*)(As + (i * 16 + ccol) * astr + k0 + q * 8);
    #pragma unroll
    for (int i = 0; i < 4; i++)
      #pragma unroll
      for (int j = 0; j < 4; j++)
        acc[i][j] = __builtin_amdgcn_mfma_f32_16x16x32_bf16(af[i], bfr[j], acc[i][j], 0, 0, 0);
  }

  // ---- bias ----  C/D layout: col = ccol, row = i*16 + 4q + r2  [m89-verified]
  float bv[4];
  #pragma unroll
  for (int j = 0; j < 4; j++) bv[j] = bias[wave * 64 + j * 16 + ccol];
  #pragma unroll
  for (int i = 0; i < 4; i++)
    #pragma unroll
    for (int j = 0; j < 4; j++)
      #pragma unroll
      for (int r2 = 0; r2 < 4; r2++) acc[i][j][r2] += bv[j];

  // ---- per-wave row stats over its 64 cols ----
  #pragma unroll
  for (int i = 0; i < 4; i++)
    #pragma unroll
    for (int r2 = 0; r2 < 4; r2++) {
      float m = fmaxf(fmaxf(acc[i][0][r2], acc[i][1][r2]), fmaxf(acc[i][2][r2], acc[i][3][r2]));
      #pragma unroll
      for (int off = 1; off < 16; off <<= 1) m = fmaxf(m, __shfl_xor(m, off, 64));
      float s = 0.f;
      #pragma unroll
      for (int j = 0; j < 4; j++) s += exp2f((acc[i][j][r2] - m) * L2E);
      #pragma unroll
      for (int off = 1; off < 16; off <<= 1) s += __shfl_xor(s, off, 64);
      if (ccol == 0) {
        const int row = i * 16 + 4 * q + r2;
        red_mx[row * 16 + wave] = m;
        red_sm[row * 16 + wave] = s;
      }
    }
  __syncthreads();

  // ---- cross-wave lse per row ----
  if (tid < 64) {
    float M = -INFINITY;
    #pragma unroll
    for (int w = 0; w < 16; w++) M = fmaxf(M, red_mx[tid * 16 + w]);
    float S = 0.f;
    #pragma unroll
    for (int w = 0; w < 16; w++) S += red_sm[tid * 16 + w] * exp2f((red_mx[tid * 16 + w] - M) * L2E);
    lse2s[tid] = M * L2E + log2f(S);
  }
  __syncthreads();

  // ---- blank-column probs (col 0 lives in wave 0) ----
  if (wave == 0 && ccol == 0) {
    #pragma unroll
    for (int i = 0; i < 4; i++)
      #pragma unroll
      for (int r2 = 0; r2 < 4; r2++) {
        const int row = i * 16 + 4 * q + r2;
        pblank[row] = exp2f(acc[i][0][r2] * L2E - lse2s[row]);
      }
  }

  // ---- odd-s entries: each label belongs to exactly one wave ----
  // ALL acc indices compile-time: unroll j, predicate on wave-uniform j==jl
  // (s_cbranch_execz skips 3 of 4) + per-lane ccol match.
  const int b = m0 / T;
  const int Lb = tlen[b];
  const int S = 2 * Lb + 1;
  const int* tg = target + b * L;
  for (int li = 0; li < Lb; li++) {
    const int lbl = tg[li];
    if ((lbl >> 6) != wave) continue;           // wave-uniform skip
    const int jl = (lbl >> 4) & 3;              // wave-uniform
    const bool mine = (ccol == (lbl & 15));     // per-lane
    #pragma unroll
    for (int j = 0; j < 4; j++) {
      if (j == jl && mine) {
        #pragma unroll
        for (int i = 0; i < 4; i++)
          #pragma unroll
          for (int r2 = 0; r2 < 4; r2++) {
            const int row = i * 16 + 4 * q + r2;
            pext[(size_t)(m0 + row) * SPAD + 2 * li + 1] =
                exp2f(acc[i][j][r2] * L2E - lse2s[row]);
          }
      }
    }
  }
  __syncthreads();   // pblank ready

  // ---- even-s + tail: wave handles rows wave*4..+3 ----
  #pragma unroll
  for (int rr = 0; rr < 4; rr++) {
    const int row = wave * 4 + rr;
    const float pb = pblank[row];
    float* prow = pext + (size_t)(m0 + row) * SPAD;
    for (int s = lane; s < SPAD; s += 64) {
      if (s >= S)       prow[s] = 0.f;
      else if (!(s & 1)) prow[s] = pb;
    }
  }
}

// ---------------- k_ctc: scaled linear-domain CTC forward, 1 wave per batch ----------------
__device__ __forceinline__ float wave_shr1(float x) {   // lane l <- lane l-1, lane0 <- 0
  return __int_as_float(__builtin_amdgcn_update_dpp(0, __float_as_int(x), 0x138, 0xf, 0xf, true));
}
__device__ __forceinline__ float wave_max_nonneg(float x) {
  x = fmaxf(x, __int_as_float(__builtin_amdgcn_update_dpp(0, __float_as_int(x), 0x111, 0xf, 0xf, true)));
  x = fmaxf(x, __int_as_float(__builtin_amdgcn_update_dpp(0, __float_as_int(x), 0x112, 0xf, 0xf, true)));
  x = fmaxf(x, __int_as_float(__builtin_amdgcn_update_dpp(0, __float_as_int(x), 0x114, 0xf, 0xf, true)));
  x = fmaxf(x, __int_as_float(__builtin_amdgcn_update_dpp(0, __float_as_int(x), 0x118, 0xf, 0xf, true)));
  x = fmaxf(x, __int_as_float(__builtin_amdgcn_update_dpp(0, __float_as_int(x), 0x142, 0xf, 0xf, true)));
  x = fmaxf(x, __int_as_float(__builtin_amdgcn_update_dpp(0, __float_as_int(x), 0x143, 0xf, 0xf, true)));
  return __int_as_float(__builtin_amdgcn_readlane(__float_as_int(x), 63));
}

__device__ __forceinline__ void load8(float4* __restrict__ p, float* __restrict__ p4,
                                      const float* __restrict__ pb, int t0, int lane) {
  #pragma unroll
  for (int k = 0; k < 8; k++) {
    const float* row = pb + (size_t)(t0 + k) * SPAD;
    p[k] = *(const float4*)(row + (lane << 2));
    p4[k] = row[256];               // wave-broadcast load
  }
}

__global__ __launch_bounds__(64, 1) void k_ctc(const float* __restrict__ pext,
                                               const int* __restrict__ target,
                                               const int* __restrict__ ilen,
                                               const int* __restrict__ tlen,
                                               float* __restrict__ out, int T, int L) {
  const int b = blockIdx.x;
  const int lane = threadIdx.x;          // 64 threads = 1 wave
  const int B = gridDim.x;
  const int Tb = ilen[b];
  const int Lb = tlen[b];
  const int S = 2 * Lb + 1;
  const int* tg = target + b * L;

  const int s1 = 4 * lane + 1, s3 = 4 * lane + 3;
  float sk1 = 0.f, sk3 = 0.f;
  if (s1 >= 3 && s1 < S) sk1 = (tg[(s1 - 1) >> 1] != tg[(s1 - 3) >> 1]) ? 1.f : 0.f;
  if (s3 >= 3 && s3 < S) sk3 = (tg[(s3 - 1) >> 1] != tg[(s3 - 3) >> 1]) ? 1.f : 0.f;

  const float* pb = pext + (size_t)b * T * SPAD;
  const float4 p0 = *(const float4*)(pb + (lane << 2));
  float a0 = (lane == 0) ? p0.x : 0.f;
  float a1 = (lane == 0) ? p0.y : 0.f;
  float a2 = 0.f, a3 = 0.f, a4 = 0.f;
  float log2C = 0.f;

  #define CTC_STEP(PP, P4) {                                            \
    const float pm3 = wave_shr1(a3);                                    \
    const float a255 = __int_as_float(__builtin_amdgcn_readlane(__float_as_int(a3), 63)); \
    const float n0v = (a0 + pm3) * (PP).x;                              \
    const float n1v = (a1 + a0 + sk1 * pm3) * (PP).y;                   \
    const float n2v = (a2 + a1) * (PP).z;                               \
    const float n3v = (a3 + a2 + sk3 * a1) * (PP).w;                    \
    const float n4v = (a4 + a255) * (P4);                               \
    a0 = n0v; a1 = n1v; a2 = n2v; a3 = n3v; a4 = n4v; }

  #define RENORM {                                                      \
    float m = fmaxf(fmaxf(fmaxf(a0, a1), fmaxf(a2, a3)), a4);           \
    m = wave_max_nonneg(m);                                             \
    const int e = (int)((__float_as_uint(m) >> 23) & 255u) - 127;       \
    const float scale = __uint_as_float((uint32_t)(127 - e) << 23);     \
    a0 *= scale; a1 *= scale; a2 *= scale; a3 *= scale; a4 *= scale;    \
    log2C += (float)e; }

  float4 Pa[8], Pb_[8], Pc[8], Pd[8];
  float Qa[8], Qb[8], Qc[8], Qd[8];
  int t0 = 1;
  bool done = false;
  load8(Pa, Qa, pb, t0, lane);
  load8(Pb_, Qb, pb, t0 + 8, lane);
  load8(Pc, Qc, pb, t0 + 16, lane);
  __builtin_amdgcn_sched_barrier(0);

  #define PHASE(LP, LQ, CP, CQ) {                                       \
    if (t0 + 8 <= Tb) {                                                 \
      load8(LP, LQ, pb, t0 + 24, lane);                                 \
      __builtin_amdgcn_sched_barrier(0);                                \
      _Pragma("unroll")                                                 \
      for (int k = 0; k < 8; k++) CTC_STEP(CP[k], CQ[k]);               \
      RENORM; t0 += 8;                                                  \
    } else {                                                            \
      _Pragma("unroll")                                                 \
      for (int k = 0; k < 8; k++) { if (t0 + k < Tb) CTC_STEP(CP[k], CQ[k]); } \
      RENORM; done = true;                                              \
    } }

  while (!done) {
    PHASE(Pd, Qd, Pa, Qa); if (done) break;
    PHASE(Pa, Qa, Pb_, Qb); if (done) break;
    PHASE(Pb_, Qb, Pc, Qc); if (done) break;
    PHASE(Pc, Qc, Pd, Qd);
  }

  __shared__ float abuf[257];
  abuf[4 * lane + 0] = a0; abuf[4 * lane + 1] = a1;
  abuf[4 * lane + 2] = a2; abuf[4 * lane + 3] = a3;
  if (lane == 63) abuf[256] = a4;
  __syncthreads();
  if (lane == 0) {
    const float ssum = abuf[2 * Lb - 1] + abuf[2 * Lb];
    const float ll = (log2f(ssum) + log2C) * LN2;
    float nll = -ll;
    if (!(nll < 1e29f)) nll = 0.f;                 // zero_infinity (also catches inf/nan)
    atomicAdd(out, nll / ((float)(Lb > 0 ? Lb : 1) * (float)B));
  }
}

// ---------------------------------------------------------------------------
extern "C" void kernel_launch(void* const* d_in, const int* in_sizes, int n_in,
                              void* d_out, int out_size, void* d_ws, size_t ws_size,
                              hipStream_t stream) {
  const float* x      = (const float*)d_in[0];
  const float* W      = (const float*)d_in[1];
  const float* bias   = (const float*)d_in[2];
  const int*  target  = (const int*)d_in[3];
  const int*  ilen    = (const int*)d_in[4];
  const int*  tlen    = (const int*)d_in[5];

  const int B = in_sizes[4];
  const int V = in_sizes[2];
  const int D = in_sizes[1] / V;
  const int T = in_sizes[0] / (B * D);
  const int L = in_sizes[3] / B;
  const int M = B * T;

  char* ws = (char*)d_ws;
  const size_t xb_bytes = (size_t)M * D * 2;
  const size_t wt_bytes = (size_t)V * D * 2;
  uint16_t* xb = (uint16_t*)ws;
  uint16_t* Wt = (uint16_t*)(ws + xb_bytes);
  float* pext = (float*)(ws + xb_bytes + wt_bytes);

  const long long nx = (long long)M * D;
  const int nconv = (int)((nx / 8 + 255) / 256);
  const int ntrans = (V / 32) * (D / 32);
  k_prep<<<nconv + ntrans, 256, 0, stream>>>(x, xb, nx, W, Wt, D, V, (float*)d_out, nconv);

  const int smem = 64 * (D + 8) * 2 + 64 * 16 * 4 * 2 + 64 * 4 * 2;   // As | red | lse+pblank
  hipFuncSetAttribute((const void*)k_fused, hipFuncAttributeMaxDynamicSharedMemorySize, smem);
  k_fused<<<M / 64, 1024, smem, stream>>>(xb, Wt, bias, target, tlen, pext, T, D, L);

  k_ctc<<<B, 64, 0, stream>>>(pext, target, ilen, tlen, (float*)d_out, T, L);
}